// Round 4
// baseline (5866.502 us; speedup 1.0000x reference)
//
#include <hip/hip_runtime.h>

#define NBATCH 128
#define TSTEPS 128
#define NS 64
#define NC 32
#define NTOT 96

// ---- LDS layout (floats) ----
#define SV    0        // V [64][68]  (symmetric)
#define SF    4352     // F [64][100] cols 0..63=A row, 64..95=B row
#define SFT   10752    // FtVT [64][100]: FtVT[k][i] = (F^T V)[i][k]; later W [64][68]
#define SQB   17152    // Qbar [96][100]
#define SM    26752    // Minv [32][33]
#define SKT   27808    // Kt [64][33]: Kt[m][r] = K[r][m]
#define SQBAR 29920    // qbar [96]
#define SW1   30016    // w1 [64]
#define SVV   30080    // v [64]
#define SCV   30144    // cvec ping-pong [2][64]
#define SKV   30272    // kv ping-pong [2][32]
#define SZ    30336    // forward state z = [x(64) | u(32)]
#define SP2   30432    // j-split partial buffer (P1: [64][100], P2: [96][100])
#define SMEM_FLOATS 40032
#define SMEM_BYTES (SMEM_FLOATS * 4)   // 160128 B <= 163840

// NOTE: workspace layout assumes ws_size >= (NBATCH*TSTEPS*NC*NS + NBATCH*TSTEPS*NC)*4
//       = 136.3 MB (K gains + k vectors staged for the forward pass).

__global__ void __launch_bounds__(256, 1)
lqr_kernel(const float* __restrict__ Qg, const float* __restrict__ pg,
           const float* __restrict__ Ag, const float* __restrict__ Bg,
           const float* __restrict__ cg, const float* __restrict__ x0g,
           float* __restrict__ outg, float* __restrict__ wsg)
{
    extern __shared__ float s[];
    const int b    = blockIdx.x;
    const int tid  = threadIdx.x;
    const int lane = tid & 63;

    const float* Qb_g = Qg + (size_t)b * TSTEPS * NTOT * NTOT;
    const float* p_g  = pg + (size_t)b * TSTEPS * NTOT;
    const float* A_g  = Ag + (size_t)b * TSTEPS * NS * NS;
    const float* B_g  = Bg + (size_t)b * TSTEPS * NS * NC;
    const float* c_g  = cg + (size_t)b * TSTEPS * NS;
    float* K_ws  = wsg + (size_t)b * TSTEPS * NC * NS;
    float* k_ws  = wsg + (size_t)NBATCH * TSTEPS * NC * NS + (size_t)b * TSTEPS * NC;
    float* tau_g = outg + (size_t)b * TSTEPS * NTOT;

    // stage A(t),B(t)->F ; c(t)->cvec[par]   (threads 64..255)
    auto stage_bwd = [&](int tsrc) {
        if (tid >= 64 && tid < 192) {
            const int q = tid - 64, j = q >> 1, i0 = (q & 1) * 32;
            const float4* src = (const float4*)(A_g + ((size_t)tsrc * NS + j) * NS + i0);
            float4 tmp[8];
            #pragma unroll
            for (int z = 0; z < 8; ++z) tmp[z] = src[z];
            float* dst = &s[SF + j * 100 + i0];
            #pragma unroll
            for (int z = 0; z < 8; ++z) *(float4*)(dst + 4 * z) = tmp[z];
        } else if (tid >= 192) {
            const int j = tid - 192;
            const float4* src = (const float4*)(B_g + ((size_t)tsrc * NS + j) * NC);
            float4 tmp[8];
            #pragma unroll
            for (int z = 0; z < 8; ++z) tmp[z] = src[z];
            float* dst = &s[SF + j * 100 + 64];
            #pragma unroll
            for (int z = 0; z < 8; ++z) *(float4*)(dst + 4 * z) = tmp[z];
            s[SCV + ((tsrc & 1) << 6) + j] = c_g[(size_t)tsrc * NS + j];
        }
    };

    // ---------------- prologue: V = 0, v = 0, stage t = T-1 ----------------
    if (tid < 64) {
        #pragma unroll 4
        for (int k = 0; k < 68; ++k) s[SV + tid * 68 + k] = 0.f;
        s[SVV + tid] = 0.f;
    } else {
        stage_bwd(TSTEPS - 1);
    }
    __syncthreads();

    // ======================= backward Riccati scan =======================
    for (int t = TSTEPS - 1; t >= 0; --t) {
        const int par = t & 1;

        // ---- P0: w1[j] = v[j] + sum_k V[j][k] c[k]   (V symmetric: read V[k][j])
        if (tid < 128) {
            const int j = tid >> 1;
            const int kh = (tid & 1) * 32;
            float acc = 0.f;
            #pragma unroll 8
            for (int k = kh; k < kh + 32; ++k)
                acc = fmaf(s[SV + k * 68 + j], s[SCV + (par << 6) + k], acc);
            acc += __shfl_xor(acc, 1);
            if ((tid & 1) == 0) s[SW1 + j] = acc + s[SVV + j];
        }
        __syncthreads();

        // ---- P1: FtVT[k][i] = sum_j F[j][i] V[j][k] — 2-way j-split, all 4 waves.
        //      half0 (tid<128): j in [0,32)  -> partial directly into SFT
        //      half1 (tid>=128): j in [32,64) -> partial into SP2
        {
            const int tl   = tid & 127;
            const int half = tid >> 7;
            const int i0 = (tl >> 3) * 6;
            const int k0 = (tl & 7) * 8;
            const int jb = half * 32;
            float acc[6][8];
            #pragma unroll
            for (int z = 0; z < 6; ++z)
                #pragma unroll
                for (int k = 0; k < 8; ++k) acc[z][k] = 0.f;
            for (int jj = 0; jj < 32; ++jj) {
                const int j = jb + jj;
                float f[6];
                float2 t0 = *(const float2*)&s[SF + j * 100 + i0];
                float2 t1 = *(const float2*)&s[SF + j * 100 + i0 + 2];
                float2 t2 = *(const float2*)&s[SF + j * 100 + i0 + 4];
                f[0] = t0.x; f[1] = t0.y; f[2] = t1.x; f[3] = t1.y; f[4] = t2.x; f[5] = t2.y;
                float v[8];
                float4 v0 = *(const float4*)&s[SV + j * 68 + k0];
                float4 v1 = *(const float4*)&s[SV + j * 68 + k0 + 4];
                v[0]=v0.x; v[1]=v0.y; v[2]=v0.z; v[3]=v0.w;
                v[4]=v1.x; v[5]=v1.y; v[6]=v1.z; v[7]=v1.w;
                #pragma unroll
                for (int z = 0; z < 6; ++z)
                    #pragma unroll
                    for (int k = 0; k < 8; ++k)
                        acc[z][k] = fmaf(f[z], v[k], acc[z][k]);
            }
            const int dst = half ? SP2 : SFT;
            #pragma unroll
            for (int k = 0; k < 8; ++k)
                #pragma unroll
                for (int z = 0; z < 6; ++z)
                    s[dst + (k0 + k) * 100 + i0 + z] = acc[z][k];
        }
        __syncthreads();

        // ---- P1r: FtVT += partial (threads 0..127) ; qbar (threads 128..223)
        if (tid < 128) {
            const int row  = tid & 63;          // k row of FtVT
            const int coff = (tid >> 6) * 48;   // cols [0,48) or [48,96)
            float* d        = &s[SFT + row * 100 + coff];
            const float* p2 = &s[SP2 + row * 100 + coff];
            #pragma unroll
            for (int z = 0; z < 12; ++z) {
                float4 a = *(float4*)(d + 4 * z);
                float4 bb = *(const float4*)(p2 + 4 * z);
                a.x += bb.x; a.y += bb.y; a.z += bb.z; a.w += bb.w;
                *(float4*)(d + 4 * z) = a;
            }
        } else if (tid < 224) {
            // qbar[i] = p[i] + sum_j F[j][i] * w1[j]
            const int i = tid - 128;
            float pi = p_g[(size_t)t * NTOT + i];
            float acc = 0.f;
            #pragma unroll 8
            for (int j = 0; j < 64; ++j)
                acc = fmaf(s[SF + j * 100 + i], s[SW1 + j], acc);
            s[SQBAR + i] = pi + acc;
        }
        __syncthreads();

        // ---- P2: Qbar[i][m] = Q[i][m] + sum_j FtVT[j][i]*F[j][m]
        //          ALL 4 waves: j-split (half0: j<32, half1: j>=32 -> SP2), then add.
        {
            const int tl   = tid & 127;
            const int half = tid >> 7;
            const int i0 = (tl >> 3) * 6;
            const int m0 = (tl & 7) * 12;
            const int j0 = half * 32;
            float4 qld[6][3];
            if (half == 0) {
                const float* qsrc = Qb_g + ((size_t)t * NTOT + i0) * NTOT + m0;
                #pragma unroll
                for (int a = 0; a < 6; ++a)
                    #pragma unroll
                    for (int zz = 0; zz < 3; ++zz)
                        qld[a][zz] = *(const float4*)(qsrc + a * NTOT + 4 * zz);
            }
            float acc[6][12];
            #pragma unroll
            for (int a = 0; a < 6; ++a)
                #pragma unroll
                for (int m = 0; m < 12; ++m) acc[a][m] = 0.f;
            for (int jj = 0; jj < 32; ++jj) {
                const int j = j0 + jj;
                float ft[6];
                float2 a0 = *(const float2*)&s[SFT + j * 100 + i0];
                float2 a1 = *(const float2*)&s[SFT + j * 100 + i0 + 2];
                float2 a2 = *(const float2*)&s[SFT + j * 100 + i0 + 4];
                ft[0]=a0.x; ft[1]=a0.y; ft[2]=a1.x; ft[3]=a1.y; ft[4]=a2.x; ft[5]=a2.y;
                float fm[12];
                float4 b0 = *(const float4*)&s[SF + j * 100 + m0];
                float4 b1 = *(const float4*)&s[SF + j * 100 + m0 + 4];
                float4 b2 = *(const float4*)&s[SF + j * 100 + m0 + 8];
                fm[0]=b0.x; fm[1]=b0.y; fm[2]=b0.z; fm[3]=b0.w;
                fm[4]=b1.x; fm[5]=b1.y; fm[6]=b1.z; fm[7]=b1.w;
                fm[8]=b2.x; fm[9]=b2.y; fm[10]=b2.z; fm[11]=b2.w;
                #pragma unroll
                for (int a = 0; a < 6; ++a)
                    #pragma unroll
                    for (int m = 0; m < 12; ++m)
                        acc[a][m] = fmaf(ft[a], fm[m], acc[a][m]);
            }
            if (half == 1) {
                #pragma unroll
                for (int a = 0; a < 6; ++a) {
                    float* drow = &s[SP2 + (i0 + a) * 100 + m0];
                    #pragma unroll
                    for (int zz = 0; zz < 3; ++zz) {
                        float4 o;
                        o.x = acc[a][4*zz+0]; o.y = acc[a][4*zz+1];
                        o.z = acc[a][4*zz+2]; o.w = acc[a][4*zz+3];
                        *(float4*)(drow + 4 * zz) = o;
                    }
                }
            }
            __syncthreads();
            if (half == 0) {
                #pragma unroll
                for (int a = 0; a < 6; ++a) {
                    const float* prow = &s[SP2 + (i0 + a) * 100 + m0];
                    float* drow = &s[SQB + (i0 + a) * 100 + m0];
                    #pragma unroll
                    for (int zz = 0; zz < 3; ++zz) {
                        float4 p1 = *(const float4*)(prow + 4 * zz);
                        float4 q = qld[a][zz];
                        float4 o;
                        o.x = q.x + acc[a][4*zz+0] + p1.x;
                        o.y = q.y + acc[a][4*zz+1] + p1.y;
                        o.z = q.z + acc[a][4*zz+2] + p1.z;
                        o.w = q.w + acc[a][4*zz+3] + p1.w;
                        *(float4*)(drow + 4 * zz) = o;
                    }
                }
            }
        }
        __syncthreads();

        // ---- P3: wave0: Gauss-Jordan inverse of Quu -> Minv ; waves1-3: stage t-1
        if (tid < 64) {
            const int j = lane & 31;
            const int h = lane >> 5;
            float m[16];
            #pragma unroll
            for (int r = 0; r < 16; ++r)
                m[r] = s[SQB + (64 + h * 16 + r) * 100 + 64 + j];
            #pragma unroll
            for (int c = 0; c < 32; ++c) {
                const int hc = c >> 4, rc = c & 15;
                float pcc  = __shfl(m[rc], c + 32 * hc);
                float pinv = 1.0f / pcc;
                float prj  = __shfl(m[rc], j + 32 * hc);   // M[c][j]
                float sc   = prj * pinv;
                const bool jc = (j == c);
                #pragma unroll
                for (int r = 0; r < 16; ++r) {
                    float colc = __shfl(m[r], c + 32 * h); // M[h*16+r][c]
                    float upd = jc ? (-colc * pinv) : fmaf(-colc, sc, m[r]);
                    if ((c & 15) == r) {
                        const bool mine = (h == hc);
                        float rowcv = jc ? pinv : sc;
                        upd = mine ? rowcv : upd;
                    }
                    m[r] = upd;
                }
            }
            #pragma unroll
            for (int r = 0; r < 16; ++r)
                s[SM + (h * 16 + r) * 33 + j] = m[r];
        } else {
            stage_bwd(t > 0 ? t - 1 : 0);
        }
        __syncthreads();

        // ---- P4: K = -Minv * Qux (threads 0..127), kv = -Minv*qu (128..159)
        if (tid < 128) {
            const int r0 = (tid >> 3) * 2;
            const int m0 = (tid & 7) * 8;
            float acc[2][8];
            #pragma unroll
            for (int rr = 0; rr < 2; ++rr)
                #pragma unroll
                for (int z = 0; z < 8; ++z) acc[rr][z] = 0.f;
            for (int l = 0; l < 32; ++l) {
                float a0 = s[SM + r0 * 33 + l];
                float a1 = s[SM + (r0 + 1) * 33 + l];
                float q[8];
                float4 q0 = *(const float4*)&s[SQB + (64 + l) * 100 + m0];
                float4 q1 = *(const float4*)&s[SQB + (64 + l) * 100 + m0 + 4];
                q[0]=q0.x; q[1]=q0.y; q[2]=q0.z; q[3]=q0.w;
                q[4]=q1.x; q[5]=q1.y; q[6]=q1.z; q[7]=q1.w;
                #pragma unroll
                for (int z = 0; z < 8; ++z) {
                    acc[0][z] = fmaf(a0, q[z], acc[0][z]);
                    acc[1][z] = fmaf(a1, q[z], acc[1][z]);
                }
            }
            #pragma unroll
            for (int rr = 0; rr < 2; ++rr) {
                const int r = r0 + rr;
                float kk[8];
                #pragma unroll
                for (int z = 0; z < 8; ++z) kk[z] = -acc[rr][z];
                #pragma unroll
                for (int z = 0; z < 8; ++z)
                    s[SKT + (m0 + z) * 33 + r] = kk[z];
                float4* g = (float4*)(K_ws + ((size_t)t * NC + r) * NS + m0);
                float4 g0, g1;
                g0.x=kk[0]; g0.y=kk[1]; g0.z=kk[2]; g0.w=kk[3];
                g1.x=kk[4]; g1.y=kk[5]; g1.z=kk[6]; g1.w=kk[7];
                g[0] = g0; g[1] = g1;
            }
        } else if (tid < 160) {
            const int r = tid - 128;
            float acc = 0.f;
            #pragma unroll 8
            for (int l = 0; l < 32; ++l)
                acc = fmaf(s[SM + r * 33 + l], s[SQBAR + 64 + l], acc);
            s[SKV + r] = -acc;
            k_ws[(size_t)t * NC + r] = -acc;
        }
        __syncthreads();

        // ---- P5: W[i][k] = sum_j Qb[64+j][i] * Kt[k][j]   (W -> SFT region)
        if (tid < 128) {
            const int i0 = (tid >> 4) * 8;
            const int k0 = (tid & 15) * 4;
            float acc[8][4];
            #pragma unroll
            for (int a = 0; a < 8; ++a)
                #pragma unroll
                for (int z = 0; z < 4; ++z) acc[a][z] = 0.f;
            for (int j = 0; j < 32; ++j) {
                float q[8];
                float4 q0 = *(const float4*)&s[SQB + (64 + j) * 100 + i0];
                float4 q1 = *(const float4*)&s[SQB + (64 + j) * 100 + i0 + 4];
                q[0]=q0.x; q[1]=q0.y; q[2]=q0.z; q[3]=q0.w;
                q[4]=q1.x; q[5]=q1.y; q[6]=q1.z; q[7]=q1.w;
                float kt[4];
                #pragma unroll
                for (int z = 0; z < 4; ++z) kt[z] = s[SKT + (k0 + z) * 33 + j];
                #pragma unroll
                for (int a = 0; a < 8; ++a)
                    #pragma unroll
                    for (int z = 0; z < 4; ++z)
                        acc[a][z] = fmaf(q[a], kt[z], acc[a][z]);
            }
            #pragma unroll
            for (int a = 0; a < 8; ++a) {
                float4 o;
                o.x = acc[a][0]; o.y = acc[a][1]; o.z = acc[a][2]; o.w = acc[a][3];
                *(float4*)&s[SFT + (i0 + a) * 68 + k0] = o;
            }
        }
        __syncthreads();

        // ---- P6: V = 0.5(Qxx+Qxx^T) + 0.5(W+W^T) ; vn = qbar_x + Qxu*kv
        {
            const int i0 = (tid >> 3) * 2;
            const int k0 = (tid & 7) * 8;
            float4 qik[2][2], wik[2][2];
            #pragma unroll
            for (int a = 0; a < 2; ++a) {
                qik[a][0] = *(const float4*)&s[SQB + (i0 + a) * 100 + k0];
                qik[a][1] = *(const float4*)&s[SQB + (i0 + a) * 100 + k0 + 4];
                wik[a][0] = *(const float4*)&s[SFT + (i0 + a) * 68 + k0];
                wik[a][1] = *(const float4*)&s[SFT + (i0 + a) * 68 + k0 + 4];
            }
            float qki[2][8], wki[2][8];
            #pragma unroll
            for (int z = 0; z < 8; ++z) {
                float2 tq = *(const float2*)&s[SQB + (k0 + z) * 100 + i0];
                qki[0][z] = tq.x; qki[1][z] = tq.y;
                float2 tw = *(const float2*)&s[SFT + (k0 + z) * 68 + i0];
                wki[0][z] = tw.x; wki[1][z] = tw.y;
            }
            #pragma unroll
            for (int a = 0; a < 2; ++a) {
                float o[8];
                #pragma unroll
                for (int z = 0; z < 8; ++z) {
                    float qv = (z < 4 ? (&qik[a][0].x)[z] : (&qik[a][1].x)[z - 4]);
                    float wv = (z < 4 ? (&wik[a][0].x)[z] : (&wik[a][1].x)[z - 4]);
                    o[z] = 0.5f * (qv + qki[a][z]) + 0.5f * (wv + wki[a][z]);
                }
                float4 o0, o1;
                o0.x=o[0]; o0.y=o[1]; o0.z=o[2]; o0.w=o[3];
                o1.x=o[4]; o1.y=o[5]; o1.z=o[6]; o1.w=o[7];
                *(float4*)&s[SV + (i0 + a) * 68 + k0]     = o0;
                *(float4*)&s[SV + (i0 + a) * 68 + k0 + 4] = o1;
            }
        }
        if (tid < 64) {
            float acc = s[SQBAR + tid];
            #pragma unroll 8
            for (int j = 0; j < 32; ++j)
                acc = fmaf(s[SQB + (64 + j) * 100 + tid], s[SKV + j], acc);
            s[SVV + tid] = acc;
        }
        __syncthreads();
    }

    // ======================= forward rollout =======================
    float4 ld[8];
    float ldx = 0.f;
    auto fwd_load = [&](int tn) {
        if (tid < 128) {
            const float4* src = (const float4*)(A_g + ((size_t)tn * NS + (tid >> 1)) * NS + (tid & 1) * 32);
            #pragma unroll
            for (int z = 0; z < 8; ++z) ld[z] = src[z];
        } else if (tid < 192) {
            const int j = tid - 128;
            const float4* src = (const float4*)(B_g + ((size_t)tn * NS + j) * NC);
            #pragma unroll
            for (int z = 0; z < 8; ++z) ld[z] = src[z];
            ldx = c_g[(size_t)tn * NS + j];
        } else {
            const int q = tid - 192, r = q >> 1, m0 = (q & 1) * 32;
            const float4* src = (const float4*)(K_ws + ((size_t)tn * NC + r) * NS + m0);
            #pragma unroll
            for (int z = 0; z < 8; ++z) ld[z] = src[z];
            if ((q & 1) == 0) ldx = k_ws[(size_t)tn * NC + r];
        }
    };
    auto fwd_write = [&](int par) {
        const int FB = par ? SFT : SF;
        const int KT = par ? SQB : SKT;
        if (tid < 128) {
            float* dst = &s[FB + (tid >> 1) * 100 + (tid & 1) * 32];
            #pragma unroll
            for (int z = 0; z < 8; ++z) *(float4*)(dst + 4 * z) = ld[z];
        } else if (tid < 192) {
            const int j = tid - 128;
            float* dst = &s[FB + j * 100 + 64];
            #pragma unroll
            for (int z = 0; z < 8; ++z) *(float4*)(dst + 4 * z) = ld[z];
            s[SCV + par * 64 + j] = ldx;
        } else {
            const int q = tid - 192, r = q >> 1, m0 = (q & 1) * 32;
            #pragma unroll
            for (int z = 0; z < 8; ++z) {
                const int base = KT + (m0 + 4 * z) * 33 + r;
                s[base]      = ld[z].x;
                s[base + 33] = ld[z].y;
                s[base + 66] = ld[z].z;
                s[base + 99] = ld[z].w;
            }
            if ((q & 1) == 0) s[SKV + par * 32 + r] = ldx;
        }
    };

    fwd_load(0);
    fwd_write(0);
    if (tid < 64) s[SZ + tid] = x0g[(size_t)b * NS + tid];
    __syncthreads();

    for (int t = 0; t < TSTEPS; ++t) {
        const int cur = t & 1, nxt = cur ^ 1;
        fwd_load(t + 1 < TSTEPS ? t + 1 : t);

        // u = K x + k
        if (tid < 64) {
            const int r  = tid >> 1;
            const int jh = (tid & 1) * 32;
            const int KT = cur ? SQB : SKT;
            float acc = 0.f;
            #pragma unroll 8
            for (int j = jh; j < jh + 32; ++j)
                acc = fmaf(s[KT + j * 33 + r], s[SZ + j], acc);
            acc += __shfl_xor(acc, 1);
            if ((tid & 1) == 0) s[SZ + 64 + r] = acc + s[SKV + cur * 32 + r];
        }
        __syncthreads();

        // tau = [x ; u] ; xn = A x + B u + c = F * z + c
        float xacc = 0.f;
        const int xi = tid >> 1;
        if (tid < 96) tau_g[(size_t)t * NTOT + tid] = s[SZ + tid];
        if (tid < 128) {
            const int FB = cur ? SFT : SF;
            const int q0 = (tid & 1) * 48;
            #pragma unroll 8
            for (int q = q0; q < q0 + 48; ++q)
                xacc = fmaf(s[FB + xi * 100 + q], s[SZ + q], xacc);
            xacc += __shfl_xor(xacc, 1);
            xacc += s[SCV + cur * 64 + xi];
        }
        __syncthreads();

        if (tid < 128 && (tid & 1) == 0) s[SZ + xi] = xacc;
        fwd_write(nxt);
        __syncthreads();
    }
}

extern "C" void kernel_launch(void* const* d_in, const int* in_sizes, int n_in,
                              void* d_out, int out_size, void* d_ws, size_t ws_size,
                              hipStream_t stream) {
    const float* Q  = (const float*)d_in[0];
    const float* p  = (const float*)d_in[1];
    const float* A  = (const float*)d_in[2];
    const float* B  = (const float*)d_in[3];
    const float* c1 = (const float*)d_in[4];
    const float* x0 = (const float*)d_in[5];
    float* out = (float*)d_out;
    float* ws  = (float*)d_ws;

    hipFuncSetAttribute((const void*)lqr_kernel,
                        hipFuncAttributeMaxDynamicSharedMemorySize, SMEM_BYTES);

    dim3 grid(NBATCH), block(256);
    lqr_kernel<<<grid, block, SMEM_BYTES, stream>>>(Q, p, A, B, c1, x0, out, ws);
}